// Round 1
// baseline (643.065 us; speedup 1.0000x reference)
//
#include <hip/hip_runtime.h>
#include <hip/hip_bf16.h>
#include <stdint.h>

#define N_NODES 50000
#define MPAD    50048          // N padded to 64-row tiles for GEMM
#define IN_DIM  256
#define HEADS   8
#define CHANS   32
#define EDGES   800000
#define EPRIME  (EDGES + N_NODES)
#define NGRAPH  64
#define GN_EPS  1e-5f
#define SEG     49             // ceil(50000/1024) for single-block scan

typedef __attribute__((ext_vector_type(8))) short short8;
typedef __attribute__((ext_vector_type(4))) float floatx4;

__device__ __forceinline__ unsigned short f2b(float f) {
    uint32_t u = __float_as_uint(f);
    u += 0x7fffu + ((u >> 16) & 1u);   // RTNE
    return (unsigned short)(u >> 16);
}
__device__ __forceinline__ float b2f(unsigned short u) {
    return __uint_as_float(((uint32_t)u) << 16);
}

// ---------- convert x (fp32 -> bf16, zero-pad rows >= N) ----------
__global__ __launch_bounds__(256) void k_prep_x(const float* __restrict__ x,
                                                unsigned short* __restrict__ Xbf) {
    int idx = blockIdx.x * 256 + threadIdx.x;     // one float4 per thread
    int row = (idx * 4) >> 8;
    ushort4 o;
    if (row < N_NODES) {
        float4 v = ((const float4*)x)[idx];
        o.x = f2b(v.x); o.y = f2b(v.y); o.z = f2b(v.z); o.w = f2b(v.w);
    } else {
        o.x = o.y = o.z = o.w = 0;
    }
    ((ushort4*)Xbf)[idx] = o;
}

// ---------- build Wt[n][k] = W[k][n] bf16, n<256 -> W_l, else W_r ----------
__global__ __launch_bounds__(256) void k_prep_w(const float* __restrict__ Wl,
                                                const float* __restrict__ Wr,
                                                unsigned short* __restrict__ Wt) {
    int idx = blockIdx.x * 256 + threadIdx.x;     // 512*256
    int n = idx >> 8, k = idx & 255;
    float v = (n < 256) ? Wl[k * 256 + n] : Wr[k * 256 + (n - 256)];
    Wt[idx] = f2b(v);
}

// ---------- GEMM: [XL | XR] = Xbf @ [W_l | W_r], MFMA 16x16x32 bf16 ----------
// grid (8 col-tiles of 64, 782 row-tiles of 64), block 256 = 4 waves.
// wave w: rows rbase+16w..+15, 4 n-tiles of 16. LDS-free; Wt is L2-resident.
__global__ __launch_bounds__(256) void k_gemm(const unsigned short* __restrict__ Xbf,
                                              const unsigned short* __restrict__ Wt,
                                              const float* __restrict__ bl,
                                              const float* __restrict__ br,
                                              unsigned short* __restrict__ XL,
                                              float* __restrict__ XR) {
    int cbase = blockIdx.x * 64;
    int rbase = blockIdx.y * 64;
    int w = threadIdx.x >> 6;
    int l = threadIdx.x & 63;
    int m = l & 15, q = l >> 4;

    floatx4 acc[4] = {{0.f,0.f,0.f,0.f},{0.f,0.f,0.f,0.f},{0.f,0.f,0.f,0.f},{0.f,0.f,0.f,0.f}};
    const unsigned short* aptr = Xbf + (size_t)(rbase + w * 16 + m) * IN_DIM + q * 8;

#pragma unroll
    for (int kk = 0; kk < IN_DIM; kk += 32) {
        short8 a = *(const short8*)(aptr + kk);
#pragma unroll
        for (int t = 0; t < 4; ++t) {
            int n = cbase + t * 16 + m;
            short8 b = *(const short8*)(Wt + (size_t)n * IN_DIM + kk + q * 8);
            acc[t] = __builtin_amdgcn_mfma_f32_16x16x32_bf16(a, b, acc[t], 0, 0, 0);
        }
    }
    // C/D layout: col = lane&15, row = (lane>>4)*4 + reg  [verified m89/m91]
#pragma unroll
    for (int t = 0; t < 4; ++t) {
        int col = cbase + t * 16 + m;
        float bv = (col < 256) ? bl[col] : br[col - 256];
#pragma unroll
        for (int i = 0; i < 4; ++i) {
            int r = rbase + w * 16 + q * 4 + i;
            if (r < N_NODES) {
                float v = acc[t][i] + bv;
                if (col < 256) XL[(size_t)r * 256 + col] = f2b(v);
                else           XR[(size_t)r * 256 + (col - 256)] = v;
            }
        }
    }
}

// ---------- edge histogram by dst ----------
__global__ __launch_bounds__(256) void k_ehist(const int* __restrict__ ei,
                                               int* __restrict__ ecount) {
    int e = blockIdx.x * 256 + threadIdx.x;
    if (e >= EPRIME) return;
    int d = (e < EDGES) ? ei[EDGES + e] : (e - EDGES);
    atomicAdd(&ecount[d], 1);
}

// ---------- node-per-graph histogram ----------
__global__ __launch_bounds__(256) void k_nhist(const int* __restrict__ batch,
                                               int* __restrict__ ncount) {
    __shared__ int hist[NGRAPH];
    if (threadIdx.x < NGRAPH) hist[threadIdx.x] = 0;
    __syncthreads();
    int i = blockIdx.x * 256 + threadIdx.x;
    if (i < N_NODES) atomicAdd(&hist[batch[i]], 1);
    __syncthreads();
    if (threadIdx.x < NGRAPH && hist[threadIdx.x]) atomicAdd(&ncount[threadIdx.x], hist[threadIdx.x]);
}

// ---------- exclusive scan of ecount (single block, thread-local segments) ----------
__global__ __launch_bounds__(1024) void k_scan(const int* __restrict__ ecount,
                                               int* __restrict__ estart,
                                               int* __restrict__ ecursor) {
    __shared__ int buf[1024];
    int t = threadIdx.x;
    int base = t * SEG;
    int loc[SEG];
    int sum = 0;
#pragma unroll
    for (int j = 0; j < SEG; ++j) {
        int i = base + j;
        int v = (i < N_NODES) ? ecount[i] : 0;
        loc[j] = sum;
        sum += v;
    }
    buf[t] = sum;
    __syncthreads();
    for (int off = 1; off < 1024; off <<= 1) {
        int v = (t >= off) ? buf[t - off] : 0;
        __syncthreads();
        buf[t] += v;
        __syncthreads();
    }
    int excl = buf[t] - sum;
#pragma unroll
    for (int j = 0; j < SEG; ++j) {
        int i = base + j;
        if (i < N_NODES) {
            int v = excl + loc[j];
            estart[i] = v;
            ecursor[i] = v;
        }
    }
}

// ---------- scatter edges into dst-sorted order (store src only) ----------
__global__ __launch_bounds__(256) void k_scatter(const int* __restrict__ ei,
                                                 int* __restrict__ ecursor,
                                                 int* __restrict__ sedge) {
    int e = blockIdx.x * 256 + threadIdx.x;
    if (e >= EPRIME) return;
    int s, d;
    if (e < EDGES) { s = ei[e]; d = ei[EDGES + e]; }
    else           { s = d = e - EDGES; }
    int pos = atomicAdd(&ecursor[d], 1);
    sedge[pos] = s;
}

// ---------- core: one wave per dst, online softmax over incoming edges ----------
// lane l -> channels 4l..4l+3, head = l>>3 (8 lanes/head cover 32 channels).
__global__ __launch_bounds__(256) void k_msg(const unsigned short* __restrict__ XL,
                                             const float* __restrict__ XR,
                                             const float* __restrict__ x,
                                             const float* __restrict__ att,
                                             const float* __restrict__ bias,
                                             const int* __restrict__ sedge,
                                             const int* __restrict__ estart,
                                             const int* __restrict__ ecount,
                                             float* __restrict__ out) {
    int d = (int)((blockIdx.x * 256 + threadIdx.x) >> 6);   // wave id == dst
    int l = threadIdx.x & 63;

    float4 xrv  = ((const float4*)(XR + (size_t)d * 256))[l];
    float4 attv = ((const float4*)att)[l];
    int s0  = estart[d];
    int cnt = ecount[d];

    float mx = -INFINITY, denom = 0.f;
    float a0 = 0.f, a1 = 0.f, a2 = 0.f, a3 = 0.f;

    for (int j = 0; j < cnt; ++j) {
        int src = sedge[s0 + j];
        ushort4 xb = ((const ushort4*)(XL + (size_t)src * 256))[l];
        float x0 = b2f(xb.x), x1 = b2f(xb.y), x2 = b2f(xb.z), x3 = b2f(xb.w);
        float e0 = x0 + xrv.x; e0 = (e0 > 0.f) ? e0 : 0.2f * e0;
        float e1 = x1 + xrv.y; e1 = (e1 > 0.f) ? e1 : 0.2f * e1;
        float e2 = x2 + xrv.z; e2 = (e2 > 0.f) ? e2 : 0.2f * e2;
        float e3 = x3 + xrv.w; e3 = (e3 > 0.f) ? e3 : 0.2f * e3;
        float pp = e0 * attv.x + e1 * attv.y + e2 * attv.z + e3 * attv.w;
        pp += __shfl_xor(pp, 1);
        pp += __shfl_xor(pp, 2);
        pp += __shfl_xor(pp, 4);        // logit for this head, in all 8 lanes
        float mn = fmaxf(mx, pp);
        float sc = __expf(mx - mn);
        float al = __expf(pp - mn);
        denom = denom * sc + al;
        a0 = a0 * sc + al * x0;
        a1 = a1 * sc + al * x1;
        a2 = a2 * sc + al * x2;
        a3 = a3 * sc + al * x3;
        mx = mn;
    }
    float inv = 1.f / (denom + 1e-16f);
    float4 xin = ((const float4*)(x + (size_t)d * 256))[l];
    float4 bv  = ((const float4*)bias)[l];
    float h0 = a0 * inv + bv.x + xin.x; h0 = (h0 > 0.f) ? h0 : (__expf(h0) - 1.f);
    float h1 = a1 * inv + bv.y + xin.y; h1 = (h1 > 0.f) ? h1 : (__expf(h1) - 1.f);
    float h2 = a2 * inv + bv.z + xin.z; h2 = (h2 > 0.f) ? h2 : (__expf(h2) - 1.f);
    float h3 = a3 * inv + bv.w + xin.w; h3 = (h3 > 0.f) ? h3 : (__expf(h3) - 1.f);
    float4 hv = make_float4(h0, h1, h2, h3);
    ((float4*)(out + (size_t)d * 256))[l] = hv;
}

// ---------- GraphNorm pass 1: per-graph channel sums (batch sorted -> flush on change)
#define GN_ROWS 128
__global__ __launch_bounds__(256) void k_gn_mean(const float* __restrict__ h,
                                                 const int* __restrict__ batch,
                                                 float* __restrict__ gsum) {
    __shared__ int bsh[GN_ROWS];
    int r0 = blockIdx.x * GN_ROWS;
    for (int j = threadIdx.x; j < GN_ROWS; j += 256) {
        int i = r0 + j;
        bsh[j] = (i < N_NODES) ? batch[i] : -1;
    }
    __syncthreads();
    int c = threadIdx.x;
    float acc = 0.f;
    int g = bsh[0];
    for (int j = 0; j < GN_ROWS; ++j) {
        int i = r0 + j;
        if (i >= N_NODES) break;
        int bg = bsh[j];
        if (bg != g) {
            atomicAdd(&gsum[g * 256 + c], acc);
            acc = 0.f; g = bg;
        }
        acc += h[(size_t)i * 256 + c];
    }
    atomicAdd(&gsum[g * 256 + c], acc);
}

// ---------- GraphNorm pass 2: per-graph sum of (h - gms*mean)^2 ----------
__global__ __launch_bounds__(256) void k_gn_var(const float* __restrict__ h,
                                                const int* __restrict__ batch,
                                                const float* __restrict__ gsum,
                                                const int* __restrict__ ncount,
                                                const float* __restrict__ gms,
                                                float* __restrict__ gvar) {
    __shared__ int bsh[GN_ROWS];
    int r0 = blockIdx.x * GN_ROWS;
    for (int j = threadIdx.x; j < GN_ROWS; j += 256) {
        int i = r0 + j;
        bsh[j] = (i < N_NODES) ? batch[i] : -1;
    }
    __syncthreads();
    int c = threadIdx.x;
    float gms_c = gms[c];
    int g = bsh[0];
    float mean = gsum[g * 256 + c] / fmaxf((float)ncount[g], 1.f);
    float acc = 0.f;
    for (int j = 0; j < GN_ROWS; ++j) {
        int i = r0 + j;
        if (i >= N_NODES) break;
        int bg = bsh[j];
        if (bg != g) {
            atomicAdd(&gvar[g * 256 + c], acc);
            acc = 0.f; g = bg;
            mean = gsum[g * 256 + c] / fmaxf((float)ncount[g], 1.f);
        }
        float v = h[(size_t)i * 256 + c] - gms_c * mean;
        acc += v * v;
    }
    atomicAdd(&gvar[g * 256 + c], acc);
}

// ---------- GraphNorm finalize (in-place on d_out) ----------
__global__ __launch_bounds__(256) void k_final(float* __restrict__ out,
                                               const int* __restrict__ batch,
                                               const float* __restrict__ gsum,
                                               const float* __restrict__ gvar,
                                               const int* __restrict__ ncount,
                                               const float* __restrict__ gnw,
                                               const float* __restrict__ gnb,
                                               const float* __restrict__ gms) {
    int idx = blockIdx.x * 256 + threadIdx.x;
    int i = idx >> 6, l = idx & 63;
    if (i >= N_NODES) return;
    int g = batch[i];
    float inv = 1.f / fmaxf((float)ncount[g], 1.f);
    float4 hv = ((const float4*)(out + (size_t)i * 256))[l];
    float4 ms = ((const float4*)(gsum + g * 256))[l];
    float4 vs = ((const float4*)(gvar + g * 256))[l];
    float4 wv = ((const float4*)gnw)[l];
    float4 bv = ((const float4*)gnb)[l];
    float4 sv = ((const float4*)gms)[l];
    float4 o;
    o.x = wv.x * (hv.x - sv.x * (ms.x * inv)) * rsqrtf(vs.x * inv + GN_EPS) + bv.x;
    o.y = wv.y * (hv.y - sv.y * (ms.y * inv)) * rsqrtf(vs.y * inv + GN_EPS) + bv.y;
    o.z = wv.z * (hv.z - sv.z * (ms.z * inv)) * rsqrtf(vs.z * inv + GN_EPS) + bv.z;
    o.w = wv.w * (hv.w - sv.w * (ms.w * inv)) * rsqrtf(vs.w * inv + GN_EPS) + bv.w;
    ((float4*)(out + (size_t)i * 256))[l] = o;
}

extern "C" void kernel_launch(void* const* d_in, const int* in_sizes, int n_in,
                              void* d_out, int out_size, void* d_ws, size_t ws_size,
                              hipStream_t stream) {
    const float* x    = (const float*)d_in[0];
    const int*   ei   = (const int*)d_in[1];
    const int*   batch= (const int*)d_in[2];
    const float* Wl   = (const float*)d_in[3];
    const float* bl   = (const float*)d_in[4];
    const float* Wr   = (const float*)d_in[5];
    const float* br   = (const float*)d_in[6];
    const float* att  = (const float*)d_in[7];
    const float* bias = (const float*)d_in[8];
    const float* gnw  = (const float*)d_in[9];
    const float* gnb  = (const float*)d_in[10];
    const float* gms  = (const float*)d_in[11];
    float* out = (float*)d_out;

    char* p = (char*)d_ws;
    auto alloc = [&](size_t bytes) -> char* {
        char* r = p;
        p += (bytes + 255) & ~(size_t)255;
        return r;
    };
    unsigned short* Xbf = (unsigned short*)alloc((size_t)MPAD * 256 * 2);
    unsigned short* Wt  = (unsigned short*)alloc((size_t)512 * 256 * 2);
    unsigned short* XL  = (unsigned short*)alloc((size_t)N_NODES * 256 * 2);
    float* XR           = (float*)alloc((size_t)N_NODES * 256 * 4);
    int* ecount         = (int*)alloc((size_t)N_NODES * 4);
    int* estart         = (int*)alloc((size_t)N_NODES * 4);
    int* ecursor        = (int*)alloc((size_t)N_NODES * 4);
    int* sedge          = (int*)alloc((size_t)EPRIME * 4);
    int* ncount         = (int*)alloc((size_t)NGRAPH * 4);
    float* gsum         = (float*)alloc((size_t)NGRAPH * 256 * 4);
    float* gvar         = (float*)alloc((size_t)NGRAPH * 256 * 4);

    hipMemsetAsync(ecount, 0, (size_t)N_NODES * 4, stream);
    hipMemsetAsync(ncount, 0, (size_t)NGRAPH * 4, stream);
    hipMemsetAsync(gsum,   0, (size_t)NGRAPH * 256 * 4, stream);
    hipMemsetAsync(gvar,   0, (size_t)NGRAPH * 256 * 4, stream);

    k_prep_x<<<MPAD * 64 / 256, 256, 0, stream>>>(x, Xbf);
    k_prep_w<<<512 * 256 / 256, 256, 0, stream>>>(Wl, Wr, Wt);

    dim3 ggrid(8, MPAD / 64);   // 8 col-tiles x 782 row-tiles
    k_gemm<<<ggrid, 256, 0, stream>>>(Xbf, Wt, bl, br, XL, XR);

    k_ehist<<<(EPRIME + 255) / 256, 256, 0, stream>>>(ei, ecount);
    k_nhist<<<(N_NODES + 255) / 256, 256, 0, stream>>>(batch, ncount);
    k_scan<<<1, 1024, 0, stream>>>(ecount, estart, ecursor);
    k_scatter<<<(EPRIME + 255) / 256, 256, 0, stream>>>(ei, ecursor, sedge);

    k_msg<<<N_NODES / 4, 256, 0, stream>>>(XL, XR, x, att, bias,
                                           sedge, estart, ecount, out);

    k_gn_mean<<<(N_NODES + GN_ROWS - 1) / GN_ROWS, 256, 0, stream>>>(out, batch, gsum);
    k_gn_var<<<(N_NODES + GN_ROWS - 1) / GN_ROWS, 256, 0, stream>>>(out, batch, gsum,
                                                                    ncount, gms, gvar);
    k_final<<<N_NODES * 64 / 256, 256, 0, stream>>>(out, batch, gsum, gvar,
                                                    ncount, gnw, gnb, gms);
}

// Round 2
// 485.789 us; speedup vs baseline: 1.3238x; 1.3238x over previous
//
#include <hip/hip_runtime.h>
#include <hip/hip_bf16.h>
#include <stdint.h>

#define N_NODES 50000
#define MPAD    50048          // 782 * 64
#define IN_DIM  256
#define EDGES   800000
#define EPRIME  (EDGES + N_NODES)
#define NGRAPH  64
#define GN_EPS  1e-5f
#define ECPAD   53248          // 1024 threads * 52, >= N_NODES, int4-aligned
#define SEG     52
#define SEG4    13

typedef __attribute__((ext_vector_type(8))) short short8;
typedef __attribute__((ext_vector_type(4))) float floatx4;

__device__ __forceinline__ unsigned short f2b(float f) {
    uint32_t u = __float_as_uint(f);
    u += 0x7fffu + ((u >> 16) & 1u);   // RTNE
    return (unsigned short)(u >> 16);
}
__device__ __forceinline__ float b2f(unsigned short u) {
    return __uint_as_float(((uint32_t)u) << 16);
}

// ---------- build Wt[n][k] = W[k][n] bf16, n<256 -> W_l, else W_r ----------
__global__ __launch_bounds__(256) void k_prep_w(const float* __restrict__ Wl,
                                                const float* __restrict__ Wr,
                                                unsigned short* __restrict__ Wt) {
    int idx = blockIdx.x * 256 + threadIdx.x;     // 512*256
    int n = idx >> 8, k = idx & 255;
    float v = (n < 256) ? Wl[k * 256 + n] : Wr[k * 256 + (n - 256)];
    Wt[idx] = f2b(v);
}

// ---------- GEMM: [XL|XR] = bf16(x) @ [W_l|W_r] ----------
// Block = 64 rows x 512 cols, 512 threads = 8 waves (wave w -> cols w*64..+63).
// A staged fp32->bf16 into XOR-swizzled LDS (read exactly once from HBM).
// B (Wt, 256 KB) is L2-resident, read direct to registers.
__global__ __launch_bounds__(512) void k_gemm(const float* __restrict__ x,
                                              const unsigned short* __restrict__ Wt,
                                              const float* __restrict__ bl,
                                              const float* __restrict__ br,
                                              unsigned short* __restrict__ XL,
                                              unsigned short* __restrict__ XR) {
    __shared__ unsigned short As[64 * 256];       // 32 KB
    int rbase = blockIdx.x * 64;
    int tid = threadIdx.x;

    // stage: 2048 chunks of 8 halves (16 B), swizzle chunk^(row&7)
#pragma unroll
    for (int it = 0; it < 4; ++it) {
        int c = it * 512 + tid;
        int row = c >> 5, ch = c & 31;
        int gr = rbase + row;
        float4 f0, f1;
        if (gr < N_NODES) {
            const float4* src = (const float4*)(x + (size_t)gr * 256 + ch * 8);
            f0 = src[0]; f1 = src[1];
        } else {
            f0 = make_float4(0.f,0.f,0.f,0.f); f1 = f0;
        }
        short8 hv;
        hv[0] = (short)f2b(f0.x); hv[1] = (short)f2b(f0.y);
        hv[2] = (short)f2b(f0.z); hv[3] = (short)f2b(f0.w);
        hv[4] = (short)f2b(f1.x); hv[5] = (short)f2b(f1.y);
        hv[6] = (short)f2b(f1.z); hv[7] = (short)f2b(f1.w);
        *(short8*)(As + row * 256 + (ch ^ (row & 7)) * 8) = hv;
    }
    __syncthreads();

    int w = tid >> 6;
    int l = tid & 63;
    int m = l & 15, q = l >> 4;

    floatx4 acc[4][4];
#pragma unroll
    for (int rf = 0; rf < 4; ++rf)
#pragma unroll
        for (int cf = 0; cf < 4; ++cf)
            acc[rf][cf] = (floatx4){0.f, 0.f, 0.f, 0.f};

    const unsigned short* wbase = Wt + (size_t)(w * 64) * 256;

#pragma unroll
    for (int kk = 0; kk < 8; ++kk) {
        short8 a[4];
#pragma unroll
        for (int rf = 0; rf < 4; ++rf) {
            int row = rf * 16 + m;
            int ch = (kk * 4 + q) ^ (row & 7);
            a[rf] = *(const short8*)(As + row * 256 + ch * 8);
        }
#pragma unroll
        for (int cf = 0; cf < 4; ++cf) {
            short8 b = *(const short8*)(wbase + (size_t)(cf * 16 + m) * 256 + kk * 32 + q * 8);
#pragma unroll
            for (int rf = 0; rf < 4; ++rf)
                acc[rf][cf] = __builtin_amdgcn_mfma_f32_16x16x32_bf16(a[rf], b, acc[rf][cf], 0, 0, 0);
        }
    }

    // C/D layout: col = lane&15, row = (lane>>4)*4 + reg
    int colbase = w * 64;
#pragma unroll
    for (int cf = 0; cf < 4; ++cf) {
        int col = colbase + cf * 16 + m;
        float bv = (col < 256) ? bl[col] : br[col - 256];
        unsigned short* dst = (col < 256) ? (XL + col) : (XR + (col - 256));
#pragma unroll
        for (int rf = 0; rf < 4; ++rf)
#pragma unroll
            for (int i = 0; i < 4; ++i) {
                int r = rbase + rf * 16 + q * 4 + i;
                if (r < N_NODES) dst[(size_t)r * 256] = f2b(acc[rf][cf][i] + bv);
            }
    }
}

// ---------- edge histogram by dst ----------
__global__ __launch_bounds__(256) void k_ehist(const int* __restrict__ ei,
                                               int* __restrict__ ecount) {
    int e = blockIdx.x * 256 + threadIdx.x;
    if (e >= EPRIME) return;
    int d = (e < EDGES) ? ei[EDGES + e] : (e - EDGES);
    atomicAdd(&ecount[d], 1);
}

// ---------- node-per-graph histogram ----------
__global__ __launch_bounds__(256) void k_nhist(const int* __restrict__ batch,
                                               int* __restrict__ ncount) {
    __shared__ int hist[NGRAPH];
    if (threadIdx.x < NGRAPH) hist[threadIdx.x] = 0;
    __syncthreads();
    int i = blockIdx.x * 256 + threadIdx.x;
    if (i < N_NODES) atomicAdd(&hist[batch[i]], 1);
    __syncthreads();
    if (threadIdx.x < NGRAPH && hist[threadIdx.x]) atomicAdd(&ncount[threadIdx.x], hist[threadIdx.x]);
}

// ---------- exclusive scan of ecount (single block, int4-vectorized) ----------
__global__ __launch_bounds__(1024) void k_scan(const int* __restrict__ ecount,
                                               int* __restrict__ estart,
                                               int* __restrict__ ecursor) {
    __shared__ int buf[1024];
    int t = threadIdx.x;
    int base = t * SEG;
    int4 v[SEG4];
    int sum = 0;
#pragma unroll
    for (int j = 0; j < SEG4; ++j) {
        v[j] = ((const int4*)(ecount + base))[j];       // padded buffer, zeros past N
        sum += v[j].x + v[j].y + v[j].z + v[j].w;
    }
    buf[t] = sum;
    __syncthreads();
    for (int off = 1; off < 1024; off <<= 1) {
        int p = (t >= off) ? buf[t - off] : 0;
        __syncthreads();
        buf[t] += p;
        __syncthreads();
    }
    int run = buf[t] - sum;
#pragma unroll
    for (int j = 0; j < SEG4; ++j) {
        int4 o;
        o.x = run;                 run += v[j].x;
        o.y = run;                 run += v[j].y;
        o.z = run;                 run += v[j].z;
        o.w = run;                 run += v[j].w;
        ((int4*)(estart + base))[j]  = o;
        ((int4*)(ecursor + base))[j] = o;
    }
}

// ---------- scatter edges into dst-sorted order (store src only) ----------
__global__ __launch_bounds__(256) void k_scatter(const int* __restrict__ ei,
                                                 int* __restrict__ ecursor,
                                                 int* __restrict__ sedge) {
    int e = blockIdx.x * 256 + threadIdx.x;
    if (e >= EPRIME) return;
    int s, d;
    if (e < EDGES) { s = ei[e]; d = ei[EDGES + e]; }
    else           { s = d = e - EDGES; }
    int pos = atomicAdd(&ecursor[d], 1);
    sedge[pos] = s;
}

// ---------- core: one wave per dst, online softmax, distance-1 prefetch ----------
__global__ __launch_bounds__(256) void k_msg(const unsigned short* __restrict__ XL,
                                             const unsigned short* __restrict__ XRb,
                                             const float* __restrict__ x,
                                             const float* __restrict__ att,
                                             const float* __restrict__ bias,
                                             const int* __restrict__ sedge,
                                             const int* __restrict__ estart,
                                             const int* __restrict__ ecount,
                                             float* __restrict__ out) {
    int d = (int)((blockIdx.x * 256 + threadIdx.x) >> 6);
    int l = threadIdx.x & 63;

    ushort4 xrb = ((const ushort4*)(XRb + (size_t)d * 256))[l];
    float xr0 = b2f(xrb.x), xr1 = b2f(xrb.y), xr2 = b2f(xrb.z), xr3 = b2f(xrb.w);
    float4 attv = ((const float4*)att)[l];
    int s0  = estart[d];
    int cnt = ecount[d];

    float mx = -INFINITY, denom = 0.f;
    float a0 = 0.f, a1 = 0.f, a2 = 0.f, a3 = 0.f;

    int src0 = sedge[s0];
    ushort4 xb_n = ((const ushort4*)(XL + (size_t)src0 * 256))[l];

    for (int j = 0; j < cnt; ++j) {
        ushort4 xb = xb_n;
        int jn = (j + 1 < cnt) ? (j + 1) : j;       // wave-uniform
        int sn = sedge[s0 + jn];
        xb_n = ((const ushort4*)(XL + (size_t)sn * 256))[l];

        float x0 = b2f(xb.x), x1 = b2f(xb.y), x2 = b2f(xb.z), x3 = b2f(xb.w);
        float e0 = x0 + xr0; e0 = (e0 > 0.f) ? e0 : 0.2f * e0;
        float e1 = x1 + xr1; e1 = (e1 > 0.f) ? e1 : 0.2f * e1;
        float e2 = x2 + xr2; e2 = (e2 > 0.f) ? e2 : 0.2f * e2;
        float e3 = x3 + xr3; e3 = (e3 > 0.f) ? e3 : 0.2f * e3;
        float pp = e0 * attv.x + e1 * attv.y + e2 * attv.z + e3 * attv.w;
        pp += __shfl_xor(pp, 1);
        pp += __shfl_xor(pp, 2);
        pp += __shfl_xor(pp, 4);        // per-head logit in all 8 lanes of the head
        float mn = fmaxf(mx, pp);
        float sc = __expf(mx - mn);
        float al = __expf(pp - mn);
        denom = denom * sc + al;
        a0 = a0 * sc + al * x0;
        a1 = a1 * sc + al * x1;
        a2 = a2 * sc + al * x2;
        a3 = a3 * sc + al * x3;
        mx = mn;
    }
    float inv = 1.f / (denom + 1e-16f);
    float4 xin = ((const float4*)(x + (size_t)d * 256))[l];
    float4 bv  = ((const float4*)bias)[l];
    float h0 = a0 * inv + bv.x + xin.x; h0 = (h0 > 0.f) ? h0 : (__expf(h0) - 1.f);
    float h1 = a1 * inv + bv.y + xin.y; h1 = (h1 > 0.f) ? h1 : (__expf(h1) - 1.f);
    float h2 = a2 * inv + bv.z + xin.z; h2 = (h2 > 0.f) ? h2 : (__expf(h2) - 1.f);
    float h3 = a3 * inv + bv.w + xin.w; h3 = (h3 > 0.f) ? h3 : (__expf(h3) - 1.f);
    ((float4*)(out + (size_t)d * 256))[l] = make_float4(h0, h1, h2, h3);
}

// ---------- GraphNorm single stats pass: per-graph sum(h) and sum(h^2) ----------
#define GN_ROWS 128
__global__ __launch_bounds__(256) void k_gn_sum(const float* __restrict__ h,
                                                const int* __restrict__ batch,
                                                float* __restrict__ gsum,
                                                float* __restrict__ gsq) {
    __shared__ int bsh[GN_ROWS];
    int r0 = blockIdx.x * GN_ROWS;
    for (int j = threadIdx.x; j < GN_ROWS; j += 256) {
        int i = r0 + j;
        bsh[j] = (i < N_NODES) ? batch[i] : -1;
    }
    __syncthreads();
    int c = threadIdx.x;
    float s1 = 0.f, s2 = 0.f;
    int g = bsh[0];
    for (int j = 0; j < GN_ROWS; ++j) {
        int i = r0 + j;
        if (i >= N_NODES) break;
        int bg = bsh[j];
        if (bg != g) {
            atomicAdd(&gsum[g * 256 + c], s1);
            atomicAdd(&gsq[g * 256 + c], s2);
            s1 = 0.f; s2 = 0.f; g = bg;
        }
        float v = h[(size_t)i * 256 + c];
        s1 += v; s2 += v * v;
    }
    atomicAdd(&gsum[g * 256 + c], s1);
    atomicAdd(&gsq[g * 256 + c], s2);
}

// ---------- GraphNorm finalize: var = E[h^2] - m^2 * s * (2 - s) ----------
__global__ __launch_bounds__(256) void k_final(float* __restrict__ out,
                                               const int* __restrict__ batch,
                                               const float* __restrict__ gsum,
                                               const float* __restrict__ gsq,
                                               const int* __restrict__ ncount,
                                               const float* __restrict__ gnw,
                                               const float* __restrict__ gnb,
                                               const float* __restrict__ gms) {
    int idx = blockIdx.x * 256 + threadIdx.x;
    int i = idx >> 6, l = idx & 63;
    if (i >= N_NODES) return;
    int g = batch[i];
    float inv = 1.f / fmaxf((float)ncount[g], 1.f);
    float4 hv = ((const float4*)(out + (size_t)i * 256))[l];
    float4 ms = ((const float4*)(gsum + g * 256))[l];
    float4 qs = ((const float4*)(gsq  + g * 256))[l];
    float4 wv = ((const float4*)gnw)[l];
    float4 bv = ((const float4*)gnb)[l];
    float4 sv = ((const float4*)gms)[l];
    float4 o;
    {
        float m = ms.x * inv, q = qs.x * inv;
        float var = q - m * m * sv.x * (2.f - sv.x);
        o.x = wv.x * (hv.x - sv.x * m) * rsqrtf(var + GN_EPS) + bv.x;
    }
    {
        float m = ms.y * inv, q = qs.y * inv;
        float var = q - m * m * sv.y * (2.f - sv.y);
        o.y = wv.y * (hv.y - sv.y * m) * rsqrtf(var + GN_EPS) + bv.y;
    }
    {
        float m = ms.z * inv, q = qs.z * inv;
        float var = q - m * m * sv.z * (2.f - sv.z);
        o.z = wv.z * (hv.z - sv.z * m) * rsqrtf(var + GN_EPS) + bv.z;
    }
    {
        float m = ms.w * inv, q = qs.w * inv;
        float var = q - m * m * sv.w * (2.f - sv.w);
        o.w = wv.w * (hv.w - sv.w * m) * rsqrtf(var + GN_EPS) + bv.w;
    }
    ((float4*)(out + (size_t)i * 256))[l] = o;
}

extern "C" void kernel_launch(void* const* d_in, const int* in_sizes, int n_in,
                              void* d_out, int out_size, void* d_ws, size_t ws_size,
                              hipStream_t stream) {
    const float* x    = (const float*)d_in[0];
    const int*   ei   = (const int*)d_in[1];
    const int*   batch= (const int*)d_in[2];
    const float* Wl   = (const float*)d_in[3];
    const float* bl   = (const float*)d_in[4];
    const float* Wr   = (const float*)d_in[5];
    const float* br   = (const float*)d_in[6];
    const float* att  = (const float*)d_in[7];
    const float* bias = (const float*)d_in[8];
    const float* gnw  = (const float*)d_in[9];
    const float* gnb  = (const float*)d_in[10];
    const float* gms  = (const float*)d_in[11];
    float* out = (float*)d_out;

    char* p = (char*)d_ws;
    auto alloc = [&](size_t bytes) -> char* {
        char* r = p;
        p += (bytes + 255) & ~(size_t)255;
        return r;
    };
    unsigned short* Wt  = (unsigned short*)alloc((size_t)512 * 256 * 2);
    unsigned short* XL  = (unsigned short*)alloc((size_t)N_NODES * 256 * 2);
    unsigned short* XRb = (unsigned short*)alloc((size_t)N_NODES * 256 * 2);
    int* ecount         = (int*)alloc((size_t)ECPAD * 4);
    int* estart         = (int*)alloc((size_t)ECPAD * 4);
    int* ecursor        = (int*)alloc((size_t)ECPAD * 4);
    int* sedge          = (int*)alloc((size_t)EPRIME * 4);
    int* ncount         = (int*)alloc((size_t)NGRAPH * 4);
    float* gsum         = (float*)alloc((size_t)2 * NGRAPH * 256 * 4);  // gsum || gsq
    float* gsq          = gsum + NGRAPH * 256;

    hipMemsetAsync(ecount, 0, (size_t)ECPAD * 4, stream);
    hipMemsetAsync(ncount, 0, (size_t)NGRAPH * 4, stream);
    hipMemsetAsync(gsum,   0, (size_t)2 * NGRAPH * 256 * 4, stream);

    k_prep_w<<<512, 256, 0, stream>>>(Wl, Wr, Wt);
    k_gemm<<<MPAD / 64, 512, 0, stream>>>(x, Wt, bl, br, XL, XRb);

    k_ehist<<<(EPRIME + 255) / 256, 256, 0, stream>>>(ei, ecount);
    k_nhist<<<(N_NODES + 255) / 256, 256, 0, stream>>>(batch, ncount);
    k_scan<<<1, 1024, 0, stream>>>(ecount, estart, ecursor);
    k_scatter<<<(EPRIME + 255) / 256, 256, 0, stream>>>(ei, ecursor, sedge);

    k_msg<<<N_NODES / 4, 256, 0, stream>>>(XL, XRb, x, att, bias,
                                           sedge, estart, ecount, out);

    k_gn_sum<<<(N_NODES + GN_ROWS - 1) / GN_ROWS, 256, 0, stream>>>(out, batch, gsum, gsq);
    k_final<<<N_NODES * 64 / 256, 256, 0, stream>>>(out, batch, gsum, gsq,
                                                    ncount, gnw, gnb, gms);
}

// Round 3
// 409.576 us; speedup vs baseline: 1.5701x; 1.1861x over previous
//
#include <hip/hip_runtime.h>
#include <hip/hip_bf16.h>
#include <stdint.h>

#define N_NODES 50000
#define MPAD    50048          // 782 * 64
#define IN_DIM  256
#define EDGES   800000
#define EPRIME  (EDGES + N_NODES)
#define NGRAPH  64
#define GN_EPS  1e-5f
#define ECPAD   53248          // 1024 * 52 >= N_NODES, int4-aligned
#define SEG     52
#define SEG4    13

typedef __attribute__((ext_vector_type(8))) short short8;
typedef __attribute__((ext_vector_type(4))) float floatx4;

__device__ __forceinline__ unsigned short f2b(float f) {
    uint32_t u = __float_as_uint(f);
    u += 0x7fffu + ((u >> 16) & 1u);   // RTNE
    return (unsigned short)(u >> 16);
}
__device__ __forceinline__ float b2f(unsigned short u) {
    return __uint_as_float(((uint32_t)u) << 16);
}

// ---------- build Wt[n][k] = W[k][n] bf16, n<256 -> W_l, else W_r ----------
__global__ __launch_bounds__(256) void k_prep_w(const float* __restrict__ Wl,
                                                const float* __restrict__ Wr,
                                                unsigned short* __restrict__ Wt) {
    int idx = blockIdx.x * 256 + threadIdx.x;     // 512*256
    int n = idx >> 8, k = idx & 255;
    float v = (n < 256) ? Wl[k * 256 + n] : Wr[k * 256 + (n - 256)];
    Wt[idx] = f2b(v);
}

// ---------- GEMM: [XL|XR] = bf16(x) @ [W_l|W_r] ----------
// Block = 64 rows x 512 cols, 512 threads = 8 waves (wave w -> cols w*64..+63).
// A staged fp32->bf16 into XOR-swizzled LDS. B (Wt, 256 KB) L2-resident.
// MFMA computed TRANSPOSED (A-slot = W rows, B-slot = X rows) so each lane
// holds 4 consecutive channels of one node -> packed 8 B stores.
__global__ __launch_bounds__(512) void k_gemm(const float* __restrict__ x,
                                              const unsigned short* __restrict__ Wt,
                                              const float* __restrict__ bl,
                                              const float* __restrict__ br,
                                              unsigned short* __restrict__ XL,
                                              unsigned short* __restrict__ XR) {
    __shared__ unsigned short As[64 * 256];       // 32 KB
    int rbase = blockIdx.x * 64;
    int tid = threadIdx.x;

#pragma unroll
    for (int it = 0; it < 4; ++it) {
        int c = it * 512 + tid;
        int row = c >> 5, ch = c & 31;
        int gr = rbase + row;
        float4 f0, f1;
        if (gr < N_NODES) {
            const float4* src = (const float4*)(x + (size_t)gr * 256 + ch * 8);
            f0 = src[0]; f1 = src[1];
        } else {
            f0 = make_float4(0.f,0.f,0.f,0.f); f1 = f0;
        }
        short8 hv;
        hv[0] = (short)f2b(f0.x); hv[1] = (short)f2b(f0.y);
        hv[2] = (short)f2b(f0.z); hv[3] = (short)f2b(f0.w);
        hv[4] = (short)f2b(f1.x); hv[5] = (short)f2b(f1.y);
        hv[6] = (short)f2b(f1.z); hv[7] = (short)f2b(f1.w);
        *(short8*)(As + row * 256 + (ch ^ (row & 7)) * 8) = hv;
    }
    __syncthreads();

    int w = tid >> 6;
    int l = tid & 63;
    int m = l & 15, q = l >> 4;

    floatx4 acc[4][4];
#pragma unroll
    for (int rf = 0; rf < 4; ++rf)
#pragma unroll
        for (int cf = 0; cf < 4; ++cf)
            acc[rf][cf] = (floatx4){0.f, 0.f, 0.f, 0.f};

    const unsigned short* wbase = Wt + (size_t)(w * 64) * 256;

#pragma unroll
    for (int kk = 0; kk < 8; ++kk) {
        short8 a[4];
#pragma unroll
        for (int rf = 0; rf < 4; ++rf) {
            int row = rf * 16 + m;
            int ch = (kk * 4 + q) ^ (row & 7);
            a[rf] = *(const short8*)(As + row * 256 + ch * 8);
        }
#pragma unroll
        for (int cf = 0; cf < 4; ++cf) {
            short8 b = *(const short8*)(wbase + (size_t)(cf * 16 + m) * 256 + kk * 32 + q * 8);
#pragma unroll
            for (int rf = 0; rf < 4; ++rf)   // A-slot = W frag -> D = C^T tile
                acc[rf][cf] = __builtin_amdgcn_mfma_f32_16x16x32_bf16(b, a[rf], acc[rf][cf], 0, 0, 0);
        }
    }

    // D layout (transposed compute): node = lane&15, channel = q*4 + reg.
    unsigned short* obase = (w < 4) ? XL : XR;
    const float* bptr = (w < 4) ? bl : br;
    int cb = (w & 3) * 64;
#pragma unroll
    for (int cf = 0; cf < 4; ++cf) {
        int chb = cb + cf * 16 + q * 4;
        float4 bv = *(const float4*)(bptr + chb);
#pragma unroll
        for (int rf = 0; rf < 4; ++rf) {
            int node = rbase + rf * 16 + m;
            ushort4 o;
            o.x = f2b(acc[rf][cf][0] + bv.x);
            o.y = f2b(acc[rf][cf][1] + bv.y);
            o.z = f2b(acc[rf][cf][2] + bv.z);
            o.w = f2b(acc[rf][cf][3] + bv.w);
            *(ushort4*)(obase + (size_t)node * 256 + chb) = o;  // pad rows exist
        }
    }
}

// ---------- fused edge-by-dst histogram + node-per-graph histogram ----------
__global__ __launch_bounds__(256) void k_hist(const int* __restrict__ ei,
                                              const int* __restrict__ batch,
                                              int* __restrict__ ecount,
                                              int* __restrict__ ncount) {
    __shared__ int hist[NGRAPH];
    if (threadIdx.x < NGRAPH) hist[threadIdx.x] = 0;
    __syncthreads();
    int e = blockIdx.x * 256 + threadIdx.x;
    if (e < EPRIME) {
        int d = (e < EDGES) ? ei[EDGES + e] : (e - EDGES);
        atomicAdd(&ecount[d], 1);
    }
    if (e < N_NODES) atomicAdd(&hist[batch[e]], 1);
    __syncthreads();
    if (threadIdx.x < NGRAPH && hist[threadIdx.x])
        atomicAdd(&ncount[threadIdx.x], hist[threadIdx.x]);
}

// ---------- exclusive scan of ecount (single block, int4-vectorized) ----------
__global__ __launch_bounds__(1024) void k_scan(const int* __restrict__ ecount,
                                               int* __restrict__ estart,
                                               int* __restrict__ ecursor) {
    __shared__ int buf[1024];
    int t = threadIdx.x;
    int base = t * SEG;
    int4 v[SEG4];
    int sum = 0;
#pragma unroll
    for (int j = 0; j < SEG4; ++j) {
        v[j] = ((const int4*)(ecount + base))[j];       // padded, zeros past N
        sum += v[j].x + v[j].y + v[j].z + v[j].w;
    }
    buf[t] = sum;
    __syncthreads();
    for (int off = 1; off < 1024; off <<= 1) {
        int p = (t >= off) ? buf[t - off] : 0;
        __syncthreads();
        buf[t] += p;
        __syncthreads();
    }
    int run = buf[t] - sum;
#pragma unroll
    for (int j = 0; j < SEG4; ++j) {
        int4 o;
        o.x = run; run += v[j].x;
        o.y = run; run += v[j].y;
        o.z = run; run += v[j].z;
        o.w = run; run += v[j].w;
        ((int4*)(estart + base))[j]  = o;
        ((int4*)(ecursor + base))[j] = o;
    }
}

// ---------- scatter edges into dst-sorted order (store src only) ----------
__global__ __launch_bounds__(256) void k_scatter(const int* __restrict__ ei,
                                                 int* __restrict__ ecursor,
                                                 int* __restrict__ sedge) {
    int e = blockIdx.x * 256 + threadIdx.x;
    if (e >= EPRIME) return;
    int s, d;
    if (e < EDGES) { s = ei[e]; d = ei[EDGES + e]; }
    else           { s = d = e - EDGES; }
    int pos = atomicAdd(&ecursor[d], 1);
    sedge[pos] = s;
}

// ---------- core: one wave per dst, direct-exp softmax, 2-edge unroll ----------
__global__ __launch_bounds__(256) void k_msg(const unsigned short* __restrict__ XL,
                                             const unsigned short* __restrict__ XRb,
                                             const float* __restrict__ x,
                                             const float* __restrict__ att,
                                             const float* __restrict__ bias,
                                             const int* __restrict__ sedge,
                                             const int* __restrict__ estart,
                                             const int* __restrict__ ecount,
                                             float* __restrict__ out) {
    int d = (int)((blockIdx.x * 256 + threadIdx.x) >> 6);
    int l = threadIdx.x & 63;

    ushort4 xrb = ((const ushort4*)(XRb + (size_t)d * 256))[l];
    float xr0 = b2f(xrb.x), xr1 = b2f(xrb.y), xr2 = b2f(xrb.z), xr3 = b2f(xrb.w);
    float4 attv = ((const float4*)att)[l];
    int s0  = estart[d];
    int cnt = ecount[d];

    float den0 = 0.f, den1 = 0.f;
    float a0 = 0.f, a1 = 0.f, a2 = 0.f, a3 = 0.f;
    float b0 = 0.f, b1 = 0.f, b2 = 0.f, b3 = 0.f;

    auto ldrow = [&](int src) -> ushort4 {
        return ((const ushort4*)(XL + (size_t)src * 256))[l];
    };

#define PROC(XB, DEN, C0, C1, C2, C3)                                   \
    {                                                                   \
        float x0 = b2f(XB.x), x1 = b2f(XB.y), x2 = b2f(XB.z), x3 = b2f(XB.w); \
        float e0 = x0 + xr0; e0 = fmaxf(e0, 0.2f * e0);                 \
        float e1 = x1 + xr1; e1 = fmaxf(e1, 0.2f * e1);                 \
        float e2 = x2 + xr2; e2 = fmaxf(e2, 0.2f * e2);                 \
        float e3 = x3 + xr3; e3 = fmaxf(e3, 0.2f * e3);                 \
        float pp = (e0 * attv.x + e1 * attv.y) + (e2 * attv.z + e3 * attv.w); \
        pp += __shfl_xor(pp, 1);                                        \
        pp += __shfl_xor(pp, 2);                                        \
        pp += __shfl_xor(pp, 4);                                        \
        float al = __expf(fminf(pp, 80.f));                             \
        DEN += al;                                                      \
        C0 = fmaf(al, x0, C0); C1 = fmaf(al, x1, C1);                   \
        C2 = fmaf(al, x2, C2); C3 = fmaf(al, x3, C3);                   \
    }

    int npair = cnt >> 1, rem = cnt & 1;
    ushort4 A0 = ldrow(sedge[s0]);
    ushort4 A1 = ldrow(sedge[s0 + (cnt > 1 ? 1 : 0)]);

    for (int p = 0; p < npair; ++p) {
        ushort4 B0 = A0, B1 = A1;
        int nb = s0 + 2 * p + 2;
        if (p + 1 < npair) {
            int sa = sedge[nb], sb = sedge[nb + 1];
            A0 = ldrow(sa);
            A1 = ldrow(sb);
        } else if (rem) {
            A0 = ldrow(sedge[s0 + cnt - 1]);
        }
        PROC(B0, den0, a0, a1, a2, a3);
        PROC(B1, den1, b0, b1, b2, b3);
    }
    if (rem) PROC(A0, den0, a0, a1, a2, a3);
#undef PROC

    float inv = 1.f / (den0 + den1 + 1e-16f);
    a0 += b0; a1 += b1; a2 += b2; a3 += b3;

    float4 xin = ((const float4*)(x + (size_t)d * 256))[l];
    float4 bv  = ((const float4*)bias)[l];
    float h0 = a0 * inv + bv.x + xin.x; h0 = (h0 > 0.f) ? h0 : (__expf(h0) - 1.f);
    float h1 = a1 * inv + bv.y + xin.y; h1 = (h1 > 0.f) ? h1 : (__expf(h1) - 1.f);
    float h2 = a2 * inv + bv.z + xin.z; h2 = (h2 > 0.f) ? h2 : (__expf(h2) - 1.f);
    float h3 = a3 * inv + bv.w + xin.w; h3 = (h3 > 0.f) ? h3 : (__expf(h3) - 1.f);
    ((float4*)(out + (size_t)d * 256))[l] = make_float4(h0, h1, h2, h3);
}

// ---------- GraphNorm stats: per-graph sum(h), sum(h^2) ----------
#define GN_ROWS 128
__global__ __launch_bounds__(256) void k_gn_sum(const float* __restrict__ h,
                                                const int* __restrict__ batch,
                                                float* __restrict__ gsum,
                                                float* __restrict__ gsq) {
    __shared__ int bsh[GN_ROWS];
    int r0 = blockIdx.x * GN_ROWS;
    for (int j = threadIdx.x; j < GN_ROWS; j += 256) {
        int i = r0 + j;
        bsh[j] = (i < N_NODES) ? batch[i] : -1;
    }
    __syncthreads();
    int c = threadIdx.x;
    float s1 = 0.f, s2 = 0.f;
    int g = bsh[0];
    for (int j = 0; j < GN_ROWS; ++j) {
        int i = r0 + j;
        if (i >= N_NODES) break;
        int bg = bsh[j];
        if (bg != g) {
            atomicAdd(&gsum[g * 256 + c], s1);
            atomicAdd(&gsq[g * 256 + c], s2);
            s1 = 0.f; s2 = 0.f; g = bg;
        }
        float v = h[(size_t)i * 256 + c];
        s1 += v; s2 += v * v;
    }
    atomicAdd(&gsum[g * 256 + c], s1);
    atomicAdd(&gsq[g * 256 + c], s2);
}

// ---------- GraphNorm finalize: var = E[h^2] - m^2 * s * (2 - s) ----------
__global__ __launch_bounds__(256) void k_final(float* __restrict__ out,
                                               const int* __restrict__ batch,
                                               const float* __restrict__ gsum,
                                               const float* __restrict__ gsq,
                                               const int* __restrict__ ncount,
                                               const float* __restrict__ gnw,
                                               const float* __restrict__ gnb,
                                               const float* __restrict__ gms) {
    int idx = blockIdx.x * 256 + threadIdx.x;
    int i = idx >> 6, l = idx & 63;
    if (i >= N_NODES) return;
    int g = batch[i];
    float inv = 1.f / fmaxf((float)ncount[g], 1.f);
    float4 hv = ((const float4*)(out + (size_t)i * 256))[l];
    float4 ms = ((const float4*)(gsum + g * 256))[l];
    float4 qs = ((const float4*)(gsq  + g * 256))[l];
    float4 wv = ((const float4*)gnw)[l];
    float4 bv = ((const float4*)gnb)[l];
    float4 sv = ((const float4*)gms)[l];
    float4 o;
    {
        float m = ms.x * inv, q = qs.x * inv;
        o.x = wv.x * (hv.x - sv.x * m) * rsqrtf(q - m * m * sv.x * (2.f - sv.x) + GN_EPS) + bv.x;
    }
    {
        float m = ms.y * inv, q = qs.y * inv;
        o.y = wv.y * (hv.y - sv.y * m) * rsqrtf(q - m * m * sv.y * (2.f - sv.y) + GN_EPS) + bv.y;
    }
    {
        float m = ms.z * inv, q = qs.z * inv;
        o.z = wv.z * (hv.z - sv.z * m) * rsqrtf(q - m * m * sv.z * (2.f - sv.z) + GN_EPS) + bv.z;
    }
    {
        float m = ms.w * inv, q = qs.w * inv;
        o.w = wv.w * (hv.w - sv.w * m) * rsqrtf(q - m * m * sv.w * (2.f - sv.w) + GN_EPS) + bv.w;
    }
    ((float4*)(out + (size_t)i * 256))[l] = o;
}

extern "C" void kernel_launch(void* const* d_in, const int* in_sizes, int n_in,
                              void* d_out, int out_size, void* d_ws, size_t ws_size,
                              hipStream_t stream) {
    const float* x    = (const float*)d_in[0];
    const int*   ei   = (const int*)d_in[1];
    const int*   batch= (const int*)d_in[2];
    const float* Wl   = (const float*)d_in[3];
    const float* bl   = (const float*)d_in[4];
    const float* Wr   = (const float*)d_in[5];
    const float* br   = (const float*)d_in[6];
    const float* att  = (const float*)d_in[7];
    const float* bias = (const float*)d_in[8];
    const float* gnw  = (const float*)d_in[9];
    const float* gnb  = (const float*)d_in[10];
    const float* gms  = (const float*)d_in[11];
    float* out = (float*)d_out;

    char* p = (char*)d_ws;
    auto alloc = [&](size_t bytes) -> char* {
        char* r = p;
        p += (bytes + 255) & ~(size_t)255;
        return r;
    };
    unsigned short* Wt  = (unsigned short*)alloc((size_t)512 * 256 * 2);
    unsigned short* XL  = (unsigned short*)alloc((size_t)MPAD * 256 * 2);
    unsigned short* XRb = (unsigned short*)alloc((size_t)MPAD * 256 * 2);
    int* ecount         = (int*)alloc((size_t)ECPAD * 4);
    int* estart         = (int*)alloc((size_t)ECPAD * 4);
    int* ecursor        = (int*)alloc((size_t)ECPAD * 4);
    int* sedge          = (int*)alloc((size_t)EPRIME * 4);
    int* ncount         = (int*)alloc((size_t)NGRAPH * 4);
    float* gsum         = (float*)alloc((size_t)2 * NGRAPH * 256 * 4);  // gsum || gsq
    float* gsq          = gsum + NGRAPH * 256;

    hipMemsetAsync(ecount, 0, (size_t)ECPAD * 4, stream);
    hipMemsetAsync(ncount, 0, (size_t)NGRAPH * 4, stream);
    hipMemsetAsync(gsum,   0, (size_t)2 * NGRAPH * 256 * 4, stream);

    k_prep_w<<<512, 256, 0, stream>>>(Wl, Wr, Wt);
    k_gemm<<<MPAD / 64, 512, 0, stream>>>(x, Wt, bl, br, XL, XRb);

    k_hist<<<(EPRIME + 255) / 256, 256, 0, stream>>>(ei, batch, ecount, ncount);
    k_scan<<<1, 1024, 0, stream>>>(ecount, estart, ecursor);
    k_scatter<<<(EPRIME + 255) / 256, 256, 0, stream>>>(ei, ecursor, sedge);

    k_msg<<<N_NODES / 4, 256, 0, stream>>>(XL, XRb, x, att, bias,
                                           sedge, estart, ecount, out);

    k_gn_sum<<<(N_NODES + GN_ROWS - 1) / GN_ROWS, 256, 0, stream>>>(out, batch, gsum, gsq);
    k_final<<<N_NODES * 64 / 256, 256, 0, stream>>>(out, batch, gsum, gsq,
                                                    ncount, gnw, gnb, gms);
}

// Round 4
// 404.916 us; speedup vs baseline: 1.5881x; 1.0115x over previous
//
#include <hip/hip_runtime.h>
#include <hip/hip_bf16.h>
#include <stdint.h>

#define N_NODES 50000
#define MPAD    50048          // 782 * 64
#define IN_DIM  256
#define EDGES   800000
#define EPRIME  (EDGES + N_NODES)
#define NGRAPH  64
#define GN_EPS  1e-5f
#define ECPAD   53248          // 1024 * 52 >= N_NODES, int4-aligned
#define SEG     52
#define SEG4    13

typedef __attribute__((ext_vector_type(8))) short short8;
typedef __attribute__((ext_vector_type(4))) float floatx4;
typedef __attribute__((ext_vector_type(2))) float float2v;

__device__ __forceinline__ unsigned short f2b(float f) {
    uint32_t u = __float_as_uint(f);
    u += 0x7fffu + ((u >> 16) & 1u);   // RTNE
    return (unsigned short)(u >> 16);
}
__device__ __forceinline__ float b2f(unsigned short u) {
    return __uint_as_float(((uint32_t)u) << 16);
}

// ---------- build Wt[n][k] = W[k][n] bf16, n<256 -> W_l, else W_r ----------
__global__ __launch_bounds__(256) void k_prep_w(const float* __restrict__ Wl,
                                                const float* __restrict__ Wr,
                                                unsigned short* __restrict__ Wt) {
    int idx = blockIdx.x * 256 + threadIdx.x;     // 512*256
    int n = idx >> 8, k = idx & 255;
    float v = (n < 256) ? Wl[k * 256 + n] : Wr[k * 256 + (n - 256)];
    Wt[idx] = f2b(v);
}

// ---------- GEMM: [XL|XR] = bf16(x) @ [W_l|W_r] ----------
__global__ __launch_bounds__(512) void k_gemm(const float* __restrict__ x,
                                              const unsigned short* __restrict__ Wt,
                                              const float* __restrict__ bl,
                                              const float* __restrict__ br,
                                              unsigned short* __restrict__ XL,
                                              unsigned short* __restrict__ XR) {
    __shared__ unsigned short As[64 * 256];       // 32 KB
    int rbase = blockIdx.x * 64;
    int tid = threadIdx.x;

#pragma unroll
    for (int it = 0; it < 4; ++it) {
        int c = it * 512 + tid;
        int row = c >> 5, ch = c & 31;
        int gr = rbase + row;
        float4 f0, f1;
        if (gr < N_NODES) {
            const float4* src = (const float4*)(x + (size_t)gr * 256 + ch * 8);
            f0 = src[0]; f1 = src[1];
        } else {
            f0 = make_float4(0.f,0.f,0.f,0.f); f1 = f0;
        }
        short8 hv;
        hv[0] = (short)f2b(f0.x); hv[1] = (short)f2b(f0.y);
        hv[2] = (short)f2b(f0.z); hv[3] = (short)f2b(f0.w);
        hv[4] = (short)f2b(f1.x); hv[5] = (short)f2b(f1.y);
        hv[6] = (short)f2b(f1.z); hv[7] = (short)f2b(f1.w);
        *(short8*)(As + row * 256 + (ch ^ (row & 7)) * 8) = hv;
    }
    __syncthreads();

    int w = tid >> 6;
    int l = tid & 63;
    int m = l & 15, q = l >> 4;

    floatx4 acc[4][4];
#pragma unroll
    for (int rf = 0; rf < 4; ++rf)
#pragma unroll
        for (int cf = 0; cf < 4; ++cf)
            acc[rf][cf] = (floatx4){0.f, 0.f, 0.f, 0.f};

    const unsigned short* wbase = Wt + (size_t)(w * 64) * 256;

#pragma unroll
    for (int kk = 0; kk < 8; ++kk) {
        short8 a[4];
#pragma unroll
        for (int rf = 0; rf < 4; ++rf) {
            int row = rf * 16 + m;
            int ch = (kk * 4 + q) ^ (row & 7);
            a[rf] = *(const short8*)(As + row * 256 + ch * 8);
        }
#pragma unroll
        for (int cf = 0; cf < 4; ++cf) {
            short8 b = *(const short8*)(wbase + (size_t)(cf * 16 + m) * 256 + kk * 32 + q * 8);
#pragma unroll
            for (int rf = 0; rf < 4; ++rf)   // A-slot = W frag -> D = C^T tile
                acc[rf][cf] = __builtin_amdgcn_mfma_f32_16x16x32_bf16(b, a[rf], acc[rf][cf], 0, 0, 0);
        }
    }

    // D layout (transposed compute): node = lane&15, channel = q*4 + reg.
    unsigned short* obase = (w < 4) ? XL : XR;
    const float* bptr = (w < 4) ? bl : br;
    int cb = (w & 3) * 64;
#pragma unroll
    for (int cf = 0; cf < 4; ++cf) {
        int chb = cb + cf * 16 + q * 4;
        float4 bv = *(const float4*)(bptr + chb);
#pragma unroll
        for (int rf = 0; rf < 4; ++rf) {
            int node = rbase + rf * 16 + m;
            ushort4 o;
            o.x = f2b(acc[rf][cf][0] + bv.x);
            o.y = f2b(acc[rf][cf][1] + bv.y);
            o.z = f2b(acc[rf][cf][2] + bv.z);
            o.w = f2b(acc[rf][cf][3] + bv.w);
            *(ushort4*)(obase + (size_t)node * 256 + chb) = o;  // pad rows exist
        }
    }
}

// ---------- fused edge-by-dst histogram + node-per-graph histogram ----------
__global__ __launch_bounds__(256) void k_hist(const int* __restrict__ ei,
                                              const int* __restrict__ batch,
                                              int* __restrict__ ecount,
                                              int* __restrict__ ncount) {
    __shared__ int hist[NGRAPH];
    if (threadIdx.x < NGRAPH) hist[threadIdx.x] = 0;
    __syncthreads();
    int e = blockIdx.x * 256 + threadIdx.x;
    if (e < EPRIME) {
        int d = (e < EDGES) ? ei[EDGES + e] : (e - EDGES);
        atomicAdd(&ecount[d], 1);
    }
    if (e < N_NODES) atomicAdd(&hist[batch[e]], 1);
    __syncthreads();
    if (threadIdx.x < NGRAPH && hist[threadIdx.x])
        atomicAdd(&ncount[threadIdx.x], hist[threadIdx.x]);
}

// ---------- exclusive scan of ecount (single block, int4-vectorized) ----------
__global__ __launch_bounds__(1024) void k_scan(const int* __restrict__ ecount,
                                               int* __restrict__ estart,
                                               int* __restrict__ ecursor) {
    __shared__ int buf[1024];
    int t = threadIdx.x;
    int base = t * SEG;
    int4 v[SEG4];
    int sum = 0;
#pragma unroll
    for (int j = 0; j < SEG4; ++j) {
        v[j] = ((const int4*)(ecount + base))[j];       // padded, zeros past N
        sum += v[j].x + v[j].y + v[j].z + v[j].w;
    }
    buf[t] = sum;
    __syncthreads();
    for (int off = 1; off < 1024; off <<= 1) {
        int p = (t >= off) ? buf[t - off] : 0;
        __syncthreads();
        buf[t] += p;
        __syncthreads();
    }
    int run = buf[t] - sum;
#pragma unroll
    for (int j = 0; j < SEG4; ++j) {
        int4 o;
        o.x = run; run += v[j].x;
        o.y = run; run += v[j].y;
        o.z = run; run += v[j].z;
        o.w = run; run += v[j].w;
        ((int4*)(estart + base))[j]  = o;
        ((int4*)(ecursor + base))[j] = o;
    }
}

// ---------- scatter edges into dst-sorted order (store src only) ----------
__global__ __launch_bounds__(256) void k_scatter(const int* __restrict__ ei,
                                                 int* __restrict__ ecursor,
                                                 int* __restrict__ sedge) {
    int e = blockIdx.x * 256 + threadIdx.x;
    if (e >= EPRIME) return;
    int s, d;
    if (e < EDGES) { s = ei[e]; d = ei[EDGES + e]; }
    else           { s = d = e - EDGES; }
    int pos = atomicAdd(&ecursor[d], 1);
    sedge[pos] = s;
}

// ---------- core: one wave per dst, packed f32 math, 4-edge pipeline ----------
__global__ __launch_bounds__(256) void k_msg(const unsigned short* __restrict__ XL,
                                             const unsigned short* __restrict__ XRb,
                                             const float* __restrict__ x,
                                             const float* __restrict__ att,
                                             const float* __restrict__ bias,
                                             const int* __restrict__ sedge,
                                             const int* __restrict__ estart,
                                             const int* __restrict__ ecount,
                                             float* __restrict__ out) {
    int d = (int)((blockIdx.x * 256 + threadIdx.x) >> 6);
    int l = threadIdx.x & 63;
    int lofs = l * 8;                 // byte offset of this lane's uint2 in a row

    // residual + params up front (overlaps with loop)
    float4 xin  = ((const float4*)(x + (size_t)d * 256))[l];
    float4 bvv  = ((const float4*)bias)[l];
    float4 attv = ((const float4*)att)[l];
    float2v att01 = {attv.x, attv.y}, att23 = {attv.z, attv.w};

    uint2 xru = ((const uint2*)(XRb + (size_t)d * 256))[l];
    float2v xr01, xr23;
    xr01[0] = __uint_as_float(xru.x << 16);
    xr01[1] = __uint_as_float(xru.x & 0xffff0000u);
    xr23[0] = __uint_as_float(xru.y << 16);
    xr23[1] = __uint_as_float(xru.y & 0xffff0000u);

    int s0  = __builtin_amdgcn_readfirstlane(estart[d]);
    int cnt = __builtin_amdgcn_readfirstlane(ecount[d]);
    int c1m = cnt - 1;

    auto ldrow = [&](int src) -> uint2 {
        size_t off = ((size_t)(uint32_t)__builtin_amdgcn_readfirstlane(src)) << 9;
        return *(const uint2*)((const char*)XL + off + lofs);
    };

    float den0 = 0.f, den1 = 0.f, den2 = 0.f, den3 = 0.f;
    float2v A01 = {0.f,0.f}, A23 = {0.f,0.f};
    float2v B01 = {0.f,0.f}, B23 = {0.f,0.f};
    float2v C01 = {0.f,0.f}, C23 = {0.f,0.f};
    float2v D01 = {0.f,0.f}, D23 = {0.f,0.f};

    auto proc = [&](uint2 U, float& den, float2v& R01, float2v& R23) {
        float2v x01, x23;
        x01[0] = __uint_as_float(U.x << 16);
        x01[1] = __uint_as_float(U.x & 0xffff0000u);
        x23[0] = __uint_as_float(U.y << 16);
        x23[1] = __uint_as_float(U.y & 0xffff0000u);
        float2v e01 = x01 + xr01, e23 = x23 + xr23;
        float2v f01 = e01 * 0.2f, f23 = e23 * 0.2f;
        e01[0] = fmaxf(e01[0], f01[0]); e01[1] = fmaxf(e01[1], f01[1]);
        e23[0] = fmaxf(e23[0], f23[0]); e23[1] = fmaxf(e23[1], f23[1]);
        float2v pp2 = e01 * att01 + e23 * att23;
        float pp = pp2[0] + pp2[1];
        // head reduce over 8 lanes: xor1, xor2 via DPP quad_perm; xor4 via swizzle
        {
            int pi = __float_as_int(pp);
            pp += __int_as_float(__builtin_amdgcn_update_dpp(0, pi, 0xB1, 0xF, 0xF, true));
            pi = __float_as_int(pp);
            pp += __int_as_float(__builtin_amdgcn_update_dpp(0, pi, 0x4E, 0xF, 0xF, true));
            pp += __shfl_xor(pp, 4);
        }
        float al = __expf(fminf(pp, 80.f));
        den += al;
        float2v al2 = {al, al};
        R01 += al2 * x01;
        R23 += al2 * x23;
    };

    // initial fill (clamped)
    uint2 P0 = ldrow(sedge[s0]);
    uint2 P1 = ldrow(sedge[s0 + min(1, c1m)]);
    uint2 P2 = ldrow(sedge[s0 + min(2, c1m)]);
    uint2 P3 = ldrow(sedge[s0 + min(3, c1m)]);

    int nq = cnt >> 2;
    for (int qq = 0; qq < nq; ++qq) {
        uint2 Q0 = P0, Q1 = P1, Q2 = P2, Q3 = P3;
        int nb = (qq + 1) << 2;
        int i0 = min(nb,     c1m), i1 = min(nb + 1, c1m);
        int i2 = min(nb + 2, c1m), i3 = min(nb + 3, c1m);
        P0 = ldrow(sedge[s0 + i0]);
        P1 = ldrow(sedge[s0 + i1]);
        P2 = ldrow(sedge[s0 + i2]);
        P3 = ldrow(sedge[s0 + i3]);
        proc(Q0, den0, A01, A23);
        proc(Q1, den1, B01, B23);
        proc(Q2, den2, C01, C23);
        proc(Q3, den3, D01, D23);
    }
    int rem = cnt & 3;
    if (rem > 0) proc(P0, den0, A01, A23);
    if (rem > 1) proc(P1, den1, B01, B23);
    if (rem > 2) proc(P2, den2, C01, C23);

    float inv = 1.f / ((den0 + den1) + (den2 + den3) + 1e-16f);
    A01 = (A01 + B01) + (C01 + D01);
    A23 = (A23 + B23) + (C23 + D23);

    float h0 = A01[0] * inv + bvv.x + xin.x; h0 = (h0 > 0.f) ? h0 : (__expf(h0) - 1.f);
    float h1 = A01[1] * inv + bvv.y + xin.y; h1 = (h1 > 0.f) ? h1 : (__expf(h1) - 1.f);
    float h2 = A23[0] * inv + bvv.z + xin.z; h2 = (h2 > 0.f) ? h2 : (__expf(h2) - 1.f);
    float h3 = A23[1] * inv + bvv.w + xin.w; h3 = (h3 > 0.f) ? h3 : (__expf(h3) - 1.f);
    ((float4*)(out + (size_t)d * 256))[l] = make_float4(h0, h1, h2, h3);
}

// ---------- GraphNorm stats: per-graph sum(h), sum(h^2) ----------
#define GN_ROWS 128
__global__ __launch_bounds__(256) void k_gn_sum(const float* __restrict__ h,
                                                const int* __restrict__ batch,
                                                float* __restrict__ gsum,
                                                float* __restrict__ gsq) {
    __shared__ int bsh[GN_ROWS];
    int r0 = blockIdx.x * GN_ROWS;
    for (int j = threadIdx.x; j < GN_ROWS; j += 256) {
        int i = r0 + j;
        bsh[j] = (i < N_NODES) ? batch[i] : -1;
    }
    __syncthreads();
    int c = threadIdx.x;
    float s1 = 0.f, s2 = 0.f;
    int g = bsh[0];
    for (int j = 0; j < GN_ROWS; ++j) {
        int i = r0 + j;
        if (i >= N_NODES) break;
        int bg = bsh[j];
        if (bg != g) {
            atomicAdd(&gsum[g * 256 + c], s1);
            atomicAdd(&gsq[g * 256 + c], s2);
            s1 = 0.f; s2 = 0.f; g = bg;
        }
        float v = h[(size_t)i * 256 + c];
        s1 += v; s2 += v * v;
    }
    atomicAdd(&gsum[g * 256 + c], s1);
    atomicAdd(&gsq[g * 256 + c], s2);
}

// ---------- GraphNorm finalize: var = E[h^2] - m^2 * s * (2 - s) ----------
__global__ __launch_bounds__(256) void k_final(float* __restrict__ out,
                                               const int* __restrict__ batch,
                                               const float* __restrict__ gsum,
                                               const float* __restrict__ gsq,
                                               const int* __restrict__ ncount,
                                               const float* __restrict__ gnw,
                                               const float* __restrict__ gnb,
                                               const float* __restrict__ gms) {
    int idx = blockIdx.x * 256 + threadIdx.x;
    int i = idx >> 6, l = idx & 63;
    if (i >= N_NODES) return;
    int g = batch[i];
    float inv = 1.f / fmaxf((float)ncount[g], 1.f);
    float4 hv = ((const float4*)(out + (size_t)i * 256))[l];
    float4 ms = ((const float4*)(gsum + g * 256))[l];
    float4 qs = ((const float4*)(gsq  + g * 256))[l];
    float4 wv = ((const float4*)gnw)[l];
    float4 bv = ((const float4*)gnb)[l];
    float4 sv = ((const float4*)gms)[l];
    float4 o;
    {
        float m = ms.x * inv, q = qs.x * inv;
        o.x = wv.x * (hv.x - sv.x * m) * rsqrtf(q - m * m * sv.x * (2.f - sv.x) + GN_EPS) + bv.x;
    }
    {
        float m = ms.y * inv, q = qs.y * inv;
        o.y = wv.y * (hv.y - sv.y * m) * rsqrtf(q - m * m * sv.y * (2.f - sv.y) + GN_EPS) + bv.y;
    }
    {
        float m = ms.z * inv, q = qs.z * inv;
        o.z = wv.z * (hv.z - sv.z * m) * rsqrtf(q - m * m * sv.z * (2.f - sv.z) + GN_EPS) + bv.z;
    }
    {
        float m = ms.w * inv, q = qs.w * inv;
        o.w = wv.w * (hv.w - sv.w * m) * rsqrtf(q - m * m * sv.w * (2.f - sv.w) + GN_EPS) + bv.w;
    }
    ((float4*)(out + (size_t)i * 256))[l] = o;
}

extern "C" void kernel_launch(void* const* d_in, const int* in_sizes, int n_in,
                              void* d_out, int out_size, void* d_ws, size_t ws_size,
                              hipStream_t stream) {
    const float* x    = (const float*)d_in[0];
    const int*   ei   = (const int*)d_in[1];
    const int*   batch= (const int*)d_in[2];
    const float* Wl   = (const float*)d_in[3];
    const float* bl   = (const float*)d_in[4];
    const float* Wr   = (const float*)d_in[5];
    const float* br   = (const float*)d_in[6];
    const float* att  = (const float*)d_in[7];
    const float* bias = (const float*)d_in[8];
    const float* gnw  = (const float*)d_in[9];
    const float* gnb  = (const float*)d_in[10];
    const float* gms  = (const float*)d_in[11];
    float* out = (float*)d_out;

    char* p = (char*)d_ws;
    auto alloc = [&](size_t bytes) -> char* {
        char* r = p;
        p += (bytes + 255) & ~(size_t)255;
        return r;
    };
    unsigned short* Wt  = (unsigned short*)alloc((size_t)512 * 256 * 2);
    unsigned short* XL  = (unsigned short*)alloc((size_t)MPAD * 256 * 2);
    unsigned short* XRb = (unsigned short*)alloc((size_t)MPAD * 256 * 2);
    int* estart         = (int*)alloc((size_t)ECPAD * 4);
    int* ecursor        = (int*)alloc((size_t)ECPAD * 4);
    int* sedge          = (int*)alloc((size_t)EPRIME * 4);
    // ---- contiguous zero-init region: ecount | ncount | gsum | gsq ----
    int* ecount         = (int*)alloc((size_t)ECPAD * 4);
    int* ncount         = (int*)alloc((size_t)NGRAPH * 4);
    float* gsum         = (float*)alloc((size_t)2 * NGRAPH * 256 * 4);  // gsum || gsq
    float* gsq          = gsum + NGRAPH * 256;
    size_t zbytes = (size_t)((char*)(gsum + 2 * NGRAPH * 256) - (char*)ecount);
    hipMemsetAsync(ecount, 0, zbytes, stream);

    k_prep_w<<<512, 256, 0, stream>>>(Wl, Wr, Wt);
    k_gemm<<<MPAD / 64, 512, 0, stream>>>(x, Wt, bl, br, XL, XRb);

    k_hist<<<(EPRIME + 255) / 256, 256, 0, stream>>>(ei, batch, ecount, ncount);
    k_scan<<<1, 1024, 0, stream>>>(ecount, estart, ecursor);
    k_scatter<<<(EPRIME + 255) / 256, 256, 0, stream>>>(ei, ecursor, sedge);

    k_msg<<<N_NODES / 4, 256, 0, stream>>>(XL, XRb, x, att, bias,
                                           sedge, estart, ecount, out);

    k_gn_sum<<<(N_NODES + GN_ROWS - 1) / GN_ROWS, 256, 0, stream>>>(out, batch, gsum, gsq);
    k_final<<<N_NODES * 64 / 256, 256, 0, stream>>>(out, batch, gsum, gsq,
                                                    ncount, gnw, gnb, gms);
}

// Round 5
// 359.681 us; speedup vs baseline: 1.7879x; 1.1258x over previous
//
#include <hip/hip_runtime.h>
#include <hip/hip_bf16.h>
#include <stdint.h>

#define N_NODES 50000
#define MPAD    50048          // 782 * 64
#define IN_DIM  256
#define EDGES   800000
#define EPRIME  (EDGES + N_NODES)
#define NGRAPH  64
#define GN_EPS  1e-5f
#define ECPAD   53248          // 208 * 256, >= N_NODES
#define NBLK    208

typedef __attribute__((ext_vector_type(8))) short short8;
typedef __attribute__((ext_vector_type(4))) float floatx4;
typedef __attribute__((ext_vector_type(2))) float float2v;

__device__ __forceinline__ uint32_t pk2bf(float a, float b) {
    union { __hip_bfloat162 h; uint32_t u; } cv;
    cv.h = __float22bfloat162_rn(make_float2(a, b));
    return cv.u;
}

__device__ __forceinline__ unsigned short f2b(float f) {
    uint32_t u = __float_as_uint(f);
    u += 0x7fffu + ((u >> 16) & 1u);   // RTNE
    return (unsigned short)(u >> 16);
}

// ---------- build Wt[n][k] = W[k][n] bf16, n<256 -> W_l, else W_r ----------
__global__ __launch_bounds__(256) void k_prep_w(const float* __restrict__ Wl,
                                                const float* __restrict__ Wr,
                                                unsigned short* __restrict__ Wt) {
    int idx = blockIdx.x * 256 + threadIdx.x;     // 512*256
    int n = idx >> 8, k = idx & 255;
    float v = (n < 256) ? Wl[k * 256 + n] : Wr[k * 256 + (n - 256)];
    Wt[idx] = f2b(v);
}

// ---------- GEMM: [XL|XR] = bf16(x) @ [W_l|W_r] ----------
__global__ __launch_bounds__(512) void k_gemm(const float* __restrict__ x,
                                              const unsigned short* __restrict__ Wt,
                                              const float* __restrict__ bl,
                                              const float* __restrict__ br,
                                              unsigned short* __restrict__ XL,
                                              unsigned short* __restrict__ XR) {
    __shared__ unsigned short As[64 * 256];       // 32 KB
    int rbase = blockIdx.x * 64;
    int tid = threadIdx.x;

#pragma unroll
    for (int it = 0; it < 4; ++it) {
        int c = it * 512 + tid;
        int row = c >> 5, ch = c & 31;
        int gr = rbase + row;
        float4 f0, f1;
        if (gr < N_NODES) {
            const float4* src = (const float4*)(x + (size_t)gr * 256 + ch * 8);
            f0 = src[0]; f1 = src[1];
        } else {
            f0 = make_float4(0.f,0.f,0.f,0.f); f1 = f0;
        }
        uint32_t p0 = pk2bf(f0.x, f0.y), p1 = pk2bf(f0.z, f0.w);
        uint32_t p2 = pk2bf(f1.x, f1.y), p3 = pk2bf(f1.z, f1.w);
        uint4 hv = make_uint4(p0, p1, p2, p3);
        *(uint4*)(As + row * 256 + (ch ^ (row & 7)) * 8) = hv;
    }
    __syncthreads();

    int w = tid >> 6;
    int l = tid & 63;
    int m = l & 15, q = l >> 4;

    floatx4 acc[4][4];
#pragma unroll
    for (int rf = 0; rf < 4; ++rf)
#pragma unroll
        for (int cf = 0; cf < 4; ++cf)
            acc[rf][cf] = (floatx4){0.f, 0.f, 0.f, 0.f};

    const unsigned short* wbase = Wt + (size_t)(w * 64) * 256;

#pragma unroll
    for (int kk = 0; kk < 8; ++kk) {
        short8 a[4];
#pragma unroll
        for (int rf = 0; rf < 4; ++rf) {
            int row = rf * 16 + m;
            int ch = (kk * 4 + q) ^ (row & 7);
            a[rf] = *(const short8*)(As + row * 256 + ch * 8);
        }
#pragma unroll
        for (int cf = 0; cf < 4; ++cf) {
            short8 b = *(const short8*)(wbase + (size_t)(cf * 16 + m) * 256 + kk * 32 + q * 8);
#pragma unroll
            for (int rf = 0; rf < 4; ++rf)   // A-slot = W frag -> D = C^T tile
                acc[rf][cf] = __builtin_amdgcn_mfma_f32_16x16x32_bf16(b, a[rf], acc[rf][cf], 0, 0, 0);
        }
    }

    // D layout (transposed compute): node = lane&15, channel = q*4 + reg.
    unsigned short* obase = (w < 4) ? XL : XR;
    const float* bptr = (w < 4) ? bl : br;
    int cb = (w & 3) * 64;
#pragma unroll
    for (int cf = 0; cf < 4; ++cf) {
        int chb = cb + cf * 16 + q * 4;
        float4 bv = *(const float4*)(bptr + chb);
#pragma unroll
        for (int rf = 0; rf < 4; ++rf) {
            int node = rbase + rf * 16 + m;
            uint2 o;
            o.x = pk2bf(acc[rf][cf][0] + bv.x, acc[rf][cf][1] + bv.y);
            o.y = pk2bf(acc[rf][cf][2] + bv.z, acc[rf][cf][3] + bv.w);
            *(uint2*)(obase + (size_t)node * 256 + chb) = o;  // pad rows exist
        }
    }
}

// ---------- fused histograms + sedge tail pad ----------
__global__ __launch_bounds__(256) void k_hist(const int* __restrict__ ei,
                                              const int* __restrict__ batch,
                                              int* __restrict__ ecount,
                                              int* __restrict__ ncount,
                                              int* __restrict__ sedge) {
    __shared__ int hist[NGRAPH];
    if (threadIdx.x < NGRAPH) hist[threadIdx.x] = 0;
    __syncthreads();
    int e = blockIdx.x * 256 + threadIdx.x;
    if (e < EPRIME) {
        int d = (e < EDGES) ? ei[EDGES + e] : (e - EDGES);
        atomicAdd(&ecount[d], 1);
    }
    if (e < N_NODES) atomicAdd(&hist[batch[e]], 1);
    if (blockIdx.x == 0 && threadIdx.x < 16) sedge[EPRIME + threadIdx.x] = 0;
    __syncthreads();
    if (threadIdx.x < NGRAPH && hist[threadIdx.x])
        atomicAdd(&ncount[threadIdx.x], hist[threadIdx.x]);
}

// ---------- 3-phase device-wide exclusive scan of ecount ----------
__global__ __launch_bounds__(256) void k_scan1(const int* __restrict__ ecount,
                                               int* __restrict__ bsum) {
    __shared__ int red[256];
    int v = ecount[blockIdx.x * 256 + threadIdx.x];
    red[threadIdx.x] = v;
    __syncthreads();
    for (int off = 128; off > 0; off >>= 1) {
        if (threadIdx.x < off) red[threadIdx.x] += red[threadIdx.x + off];
        __syncthreads();
    }
    if (threadIdx.x == 0) bsum[blockIdx.x] = red[0];
}

__global__ __launch_bounds__(256) void k_scan2(int* __restrict__ bsum) {
    __shared__ int buf[256];
    int t = threadIdx.x;
    int v = (t < NBLK) ? bsum[t] : 0;
    buf[t] = v;
    __syncthreads();
    for (int off = 1; off < 256; off <<= 1) {
        int p = (t >= off) ? buf[t - off] : 0;
        __syncthreads();
        buf[t] += p;
        __syncthreads();
    }
    if (t < NBLK) bsum[t] = buf[t] - v;      // exclusive
}

__global__ __launch_bounds__(256) void k_scan3(const int* __restrict__ ecount,
                                               const int* __restrict__ bsum,
                                               int* __restrict__ estart,
                                               int* __restrict__ ecursor) {
    __shared__ int buf[256];
    int b = blockIdx.x, t = threadIdx.x;
    int v = ecount[b * 256 + t];
    buf[t] = v;
    __syncthreads();
    for (int off = 1; off < 256; off <<= 1) {
        int p = (t >= off) ? buf[t - off] : 0;
        __syncthreads();
        buf[t] += p;
        __syncthreads();
    }
    int e = bsum[b] + buf[t] - v;
    estart[b * 256 + t]  = e;
    ecursor[b * 256 + t] = e;
}

// ---------- scatter edges into dst-sorted order (store src only) ----------
__global__ __launch_bounds__(256) void k_scatter(const int* __restrict__ ei,
                                                 int* __restrict__ ecursor,
                                                 int* __restrict__ sedge) {
    int e = blockIdx.x * 256 + threadIdx.x;
    if (e >= EPRIME) return;
    int s, d;
    if (e < EDGES) { s = ei[e]; d = ei[EDGES + e]; }
    else           { s = d = e - EDGES; }
    int pos = atomicAdd(&ecursor[d], 1);
    sedge[pos] = s;
}

// ---------- core: one wave per dst, packed f32 math, 4-edge pipeline ----------
__global__ __launch_bounds__(256) void k_msg(const unsigned short* __restrict__ XL,
                                             const unsigned short* __restrict__ XRb,
                                             const float* __restrict__ x,
                                             const float* __restrict__ att,
                                             const float* __restrict__ bias,
                                             const int* __restrict__ sedge,
                                             const int* __restrict__ estart,
                                             const int* __restrict__ ecount,
                                             float* __restrict__ out) {
    int d = (int)((blockIdx.x * 256 + threadIdx.x) >> 6);
    int l = threadIdx.x & 63;
    int lofs = l * 8;                 // byte offset of this lane's uint2 in a row

    float4 xin  = ((const float4*)(x + (size_t)d * 256))[l];
    float4 bvv  = ((const float4*)bias)[l];
    float4 attv = ((const float4*)att)[l];
    float2v att01 = {attv.x, attv.y}, att23 = {attv.z, attv.w};

    uint2 xru = ((const uint2*)(XRb + (size_t)d * 256))[l];
    float2v xr01, xr23;
    xr01[0] = __uint_as_float(xru.x << 16);
    xr01[1] = __uint_as_float(xru.x & 0xffff0000u);
    xr23[0] = __uint_as_float(xru.y << 16);
    xr23[1] = __uint_as_float(xru.y & 0xffff0000u);

    int s0  = __builtin_amdgcn_readfirstlane(estart[d]);
    int cnt = __builtin_amdgcn_readfirstlane(ecount[d]);

    auto ldrow = [&](int src) -> uint2 {
        size_t off = ((size_t)(uint32_t)__builtin_amdgcn_readfirstlane(src)) << 9;
        return *(const uint2*)((const char*)XL + off + lofs);
    };

    float den0 = 0.f, den1 = 0.f, den2 = 0.f, den3 = 0.f;
    float2v A01 = {0.f,0.f}, A23 = {0.f,0.f};
    float2v B01 = {0.f,0.f}, B23 = {0.f,0.f};
    float2v C01 = {0.f,0.f}, C23 = {0.f,0.f};
    float2v D01 = {0.f,0.f}, D23 = {0.f,0.f};

    auto proc = [&](uint2 U, float& den, float2v& R01, float2v& R23) {
        float2v x01, x23;
        x01[0] = __uint_as_float(U.x << 16);
        x01[1] = __uint_as_float(U.x & 0xffff0000u);
        x23[0] = __uint_as_float(U.y << 16);
        x23[1] = __uint_as_float(U.y & 0xffff0000u);
        float2v e01 = x01 + xr01, e23 = x23 + xr23;
        float2v f01 = e01 * 0.2f, f23 = e23 * 0.2f;
        e01[0] = fmaxf(e01[0], f01[0]); e01[1] = fmaxf(e01[1], f01[1]);
        e23[0] = fmaxf(e23[0], f23[0]); e23[1] = fmaxf(e23[1], f23[1]);
        float2v pp2 = e01 * att01 + e23 * att23;
        float pp = pp2[0] + pp2[1];
        // 8-lane head reduce: xor1, xor2 via DPP quad_perm; xor4 via ds_swizzle
        {
            int pi = __float_as_int(pp);
            pp += __int_as_float(__builtin_amdgcn_update_dpp(0, pi, 0xB1, 0xF, 0xF, true));
            pi = __float_as_int(pp);
            pp += __int_as_float(__builtin_amdgcn_update_dpp(0, pi, 0x4E, 0xF, 0xF, true));
            pp += __int_as_float(__builtin_amdgcn_ds_swizzle(__float_as_int(pp), 0x101F));
        }
        float al = __expf(fminf(pp, 80.f));
        den += al;
        float2v al2 = {al, al};
        R01 += al2 * x01;
        R23 += al2 * x23;
    };

    // unconditional fill/prefetch: sedge reads beyond this dst's range hit the
    // next dst's (valid) edges or the 16-zero tail pad — loaded but never proc'ed.
    uint2 P0 = ldrow(sedge[s0]);
    uint2 P1 = ldrow(sedge[s0 + 1]);
    uint2 P2 = ldrow(sedge[s0 + 2]);
    uint2 P3 = ldrow(sedge[s0 + 3]);

    int nq = cnt >> 2;
    for (int qq = 0; qq < nq; ++qq) {
        uint2 Q0 = P0, Q1 = P1, Q2 = P2, Q3 = P3;
        int nb = s0 + (qq + 1) * 4;
        P0 = ldrow(sedge[nb]);
        P1 = ldrow(sedge[nb + 1]);
        P2 = ldrow(sedge[nb + 2]);
        P3 = ldrow(sedge[nb + 3]);
        proc(Q0, den0, A01, A23);
        proc(Q1, den1, B01, B23);
        proc(Q2, den2, C01, C23);
        proc(Q3, den3, D01, D23);
    }
    int rem = cnt & 3;
    if (rem > 0) proc(P0, den0, A01, A23);
    if (rem > 1) proc(P1, den1, B01, B23);
    if (rem > 2) proc(P2, den2, C01, C23);

    float inv = 1.f / ((den0 + den1) + (den2 + den3) + 1e-16f);
    A01 = (A01 + B01) + (C01 + D01);
    A23 = (A23 + B23) + (C23 + D23);

    float h0 = A01[0] * inv + bvv.x + xin.x; h0 = (h0 > 0.f) ? h0 : (__expf(h0) - 1.f);
    float h1 = A01[1] * inv + bvv.y + xin.y; h1 = (h1 > 0.f) ? h1 : (__expf(h1) - 1.f);
    float h2 = A23[0] * inv + bvv.z + xin.z; h2 = (h2 > 0.f) ? h2 : (__expf(h2) - 1.f);
    float h3 = A23[1] * inv + bvv.w + xin.w; h3 = (h3 > 0.f) ? h3 : (__expf(h3) - 1.f);
    ((float4*)(out + (size_t)d * 256))[l] = make_float4(h0, h1, h2, h3);
}

// ---------- GraphNorm stats: 64-row blocks, 4-row unrolled fast path ----------
#define GN_ROWS 64
__global__ __launch_bounds__(256) void k_gn_sum(const float* __restrict__ h,
                                                const int* __restrict__ batch,
                                                float* __restrict__ gsum,
                                                float* __restrict__ gsq) {
    __shared__ int bsh[GN_ROWS];
    int r0 = blockIdx.x * GN_ROWS;
    if (threadIdx.x < GN_ROWS) {
        int i = r0 + threadIdx.x;
        bsh[threadIdx.x] = (i < N_NODES) ? batch[i] : -1;
    }
    __syncthreads();
    int c = threadIdx.x;
    float s1 = 0.f, s2 = 0.f;
    int g = bsh[0];
    for (int j = 0; j < GN_ROWS; j += 4) {
        int i = r0 + j;
        if (i >= N_NODES) break;
        bool full = (i + 3 < N_NODES);
        if (full && bsh[j] == g && bsh[j + 3] == g) {
            const float* hp = h + (size_t)i * 256 + c;
            float v0 = hp[0], v1 = hp[256], v2 = hp[512], v3 = hp[768];
            s1 += (v0 + v1) + (v2 + v3);
            s2 += (v0 * v0 + v1 * v1) + (v2 * v2 + v3 * v3);
        } else {
            for (int jj = j; jj < j + 4; ++jj) {
                int ii = r0 + jj;
                if (ii >= N_NODES) break;
                int bg = bsh[jj];
                if (bg != g) {
                    atomicAdd(&gsum[g * 256 + c], s1);
                    atomicAdd(&gsq[g * 256 + c], s2);
                    s1 = 0.f; s2 = 0.f; g = bg;
                }
                float v = h[(size_t)ii * 256 + c];
                s1 += v; s2 += v * v;
            }
        }
    }
    atomicAdd(&gsum[g * 256 + c], s1);
    atomicAdd(&gsq[g * 256 + c], s2);
}

// ---------- GraphNorm finalize: var = E[h^2] - m^2 * s * (2 - s) ----------
__global__ __launch_bounds__(256) void k_final(float* __restrict__ out,
                                               const int* __restrict__ batch,
                                               const float* __restrict__ gsum,
                                               const float* __restrict__ gsq,
                                               const int* __restrict__ ncount,
                                               const float* __restrict__ gnw,
                                               const float* __restrict__ gnb,
                                               const float* __restrict__ gms) {
    int idx = blockIdx.x * 256 + threadIdx.x;
    int i = idx >> 6, l = idx & 63;
    if (i >= N_NODES) return;
    int g = batch[i];
    float inv = 1.f / fmaxf((float)ncount[g], 1.f);
    float4 hv = ((const float4*)(out + (size_t)i * 256))[l];
    float4 ms = ((const float4*)(gsum + g * 256))[l];
    float4 qs = ((const float4*)(gsq  + g * 256))[l];
    float4 wv = ((const float4*)gnw)[l];
    float4 bv = ((const float4*)gnb)[l];
    float4 sv = ((const float4*)gms)[l];
    float4 o;
    {
        float m = ms.x * inv, q = qs.x * inv;
        o.x = wv.x * (hv.x - sv.x * m) * rsqrtf(q - m * m * sv.x * (2.f - sv.x) + GN_EPS) + bv.x;
    }
    {
        float m = ms.y * inv, q = qs.y * inv;
        o.y = wv.y * (hv.y - sv.y * m) * rsqrtf(q - m * m * sv.y * (2.f - sv.y) + GN_EPS) + bv.y;
    }
    {
        float m = ms.z * inv, q = qs.z * inv;
        o.z = wv.z * (hv.z - sv.z * m) * rsqrtf(q - m * m * sv.z * (2.f - sv.z) + GN_EPS) + bv.z;
    }
    {
        float m = ms.w * inv, q = qs.w * inv;
        o.w = wv.w * (hv.w - sv.w * m) * rsqrtf(q - m * m * sv.w * (2.f - sv.w) + GN_EPS) + bv.w;
    }
    ((float4*)(out + (size_t)i * 256))[l] = o;
}

extern "C" void kernel_launch(void* const* d_in, const int* in_sizes, int n_in,
                              void* d_out, int out_size, void* d_ws, size_t ws_size,
                              hipStream_t stream) {
    const float* x    = (const float*)d_in[0];
    const int*   ei   = (const int*)d_in[1];
    const int*   batch= (const int*)d_in[2];
    const float* Wl   = (const float*)d_in[3];
    const float* bl   = (const float*)d_in[4];
    const float* Wr   = (const float*)d_in[5];
    const float* br   = (const float*)d_in[6];
    const float* att  = (const float*)d_in[7];
    const float* bias = (const float*)d_in[8];
    const float* gnw  = (const float*)d_in[9];
    const float* gnb  = (const float*)d_in[10];
    const float* gms  = (const float*)d_in[11];
    float* out = (float*)d_out;

    char* p = (char*)d_ws;
    auto alloc = [&](size_t bytes) -> char* {
        char* r = p;
        p += (bytes + 255) & ~(size_t)255;
        return r;
    };
    unsigned short* Wt  = (unsigned short*)alloc((size_t)512 * 256 * 2);
    unsigned short* XL  = (unsigned short*)alloc((size_t)MPAD * 256 * 2);
    unsigned short* XRb = (unsigned short*)alloc((size_t)MPAD * 256 * 2);
    int* estart         = (int*)alloc((size_t)ECPAD * 4);
    int* ecursor        = (int*)alloc((size_t)ECPAD * 4);
    int* sedge          = (int*)alloc((size_t)(EPRIME + 16) * 4);
    int* bsum           = (int*)alloc((size_t)256 * 4);
    // ---- contiguous zero-init region: ecount | ncount | gsum | gsq ----
    int* ecount         = (int*)alloc((size_t)ECPAD * 4);
    int* ncount         = (int*)alloc((size_t)NGRAPH * 4);
    float* gsum         = (float*)alloc((size_t)2 * NGRAPH * 256 * 4);  // gsum || gsq
    float* gsq          = gsum + NGRAPH * 256;
    size_t zbytes = (size_t)((char*)(gsum + 2 * NGRAPH * 256) - (char*)ecount);
    hipMemsetAsync(ecount, 0, zbytes, stream);

    k_prep_w<<<512, 256, 0, stream>>>(Wl, Wr, Wt);
    k_gemm<<<MPAD / 64, 512, 0, stream>>>(x, Wt, bl, br, XL, XRb);

    k_hist<<<(EPRIME + 255) / 256, 256, 0, stream>>>(ei, batch, ecount, ncount, sedge);
    k_scan1<<<NBLK, 256, 0, stream>>>(ecount, bsum);
    k_scan2<<<1, 256, 0, stream>>>(bsum);
    k_scan3<<<NBLK, 256, 0, stream>>>(ecount, bsum, estart, ecursor);
    k_scatter<<<(EPRIME + 255) / 256, 256, 0, stream>>>(ei, ecursor, sedge);

    k_msg<<<N_NODES / 4, 256, 0, stream>>>(XL, XRb, x, att, bias,
                                           sedge, estart, ecount, out);

    k_gn_sum<<<(N_NODES + GN_ROWS - 1) / GN_ROWS, 256, 0, stream>>>(out, batch, gsum, gsq);
    k_final<<<N_NODES * 64 / 256, 256, 0, stream>>>(out, batch, gsum, gsq,
                                                    ncount, gnw, gnb, gms);
}